// Round 5
// baseline (285.712 us; speedup 1.0000x reference)
//
#include <hip/hip_runtime.h>

// Problem constants (from reference: B=256, S=64, R=128, F=1536, D=256)
constexpr int Bc = 256;
constexpr int Sc = 64;
constexpr int Rc = 128;
constexpr int Fc = 1536;
constexpr int Dc = 256;  // F/6

// ---------------------------------------------------------------------------
// Kernel 1: per-row (b,r) stats, software-pipelined grid-stride version.
// Each wave processes ROWS_PER_WAVE rows (stride = total waves); row k+1's
// 6 float4 loads are issued before row k's compute/reduce, keeping HBM
// requests in flight across the dependent shuffle chain.
// ---------------------------------------------------------------------------
constexpr int RPW = 4;  // rows per wave

__device__ __forceinline__ void accum_term(float h_re, float h_im,
                                           float r_re, float r_im,
                                           float t_re, float t_im,
                                           float& s0, float& q) {
  s0 += r_re * (h_re * t_re + h_im * t_im) + r_im * (h_re * t_im - h_im * t_re);
  q  += h_re * h_re + h_im * h_im + r_re * r_re + r_im * r_im + t_re * t_re + t_im * t_im;
}

__global__ __launch_bounds__(256) void rowstats_kernel(
    const float* __restrict__ tri, float* __restrict__ s0_out,
    float* __restrict__ q_out) {
  const int wid    = threadIdx.x >> 6;
  const int lane   = threadIdx.x & 63;
  const int gwave  = blockIdx.x * 4 + wid;      // 0 .. 8191
  const int nwaves = gridDim.x * 4;             // 8192 (= B*R / RPW)

  int row = gwave;
  float4 c0, c1, c2, c3, c4, c5;
  {
    const float4* p4 = reinterpret_cast<const float4*>(tri + (size_t)row * Fc);
    c0 = p4[lane +   0];
    c1 = p4[lane +  64];
    c2 = p4[lane + 128];
    c3 = p4[lane + 192];
    c4 = p4[lane + 256];
    c5 = p4[lane + 320];
  }

  #pragma unroll
  for (int k = 0; k < RPW; ++k) {
    float4 n0, n1, n2, n3, n4, n5;
    const int nextrow = row + nwaves;
    if (k + 1 < RPW) {
      const float4* np4 =
          reinterpret_cast<const float4*>(tri + (size_t)nextrow * Fc);
      n0 = np4[lane +   0];
      n1 = np4[lane +  64];
      n2 = np4[lane + 128];
      n3 = np4[lane + 192];
      n4 = np4[lane + 256];
      n5 = np4[lane + 320];
    }

    float s0 = 0.f, q = 0.f;
    accum_term(c0.x, c1.x, c2.x, c3.x, c4.x, c5.x, s0, q);
    accum_term(c0.y, c1.y, c2.y, c3.y, c4.y, c5.y, s0, q);
    accum_term(c0.z, c1.z, c2.z, c3.z, c4.z, c5.z, s0, q);
    accum_term(c0.w, c1.w, c2.w, c3.w, c4.w, c5.w, s0, q);

    #pragma unroll
    for (int off = 32; off > 0; off >>= 1) {
      s0 += __shfl_down(s0, off, 64);
      q  += __shfl_down(q, off, 64);
    }
    if (lane == 0) {
      s0_out[row] = s0;
      q_out[row]  = q;
    }

    row = nextrow;
    c0 = n0; c1 = n1; c2 = n2; c3 = n3; c4 = n4; c5 = n5;
  }
}

// ---------------------------------------------------------------------------
// Kernel 2: score + regul partials over (b,s,r). No atomics: one float2
// partial per block.
// ---------------------------------------------------------------------------
__global__ __launch_bounds__(256) void score_kernel(
    const float* __restrict__ alpha, const float* __restrict__ mask,
    const float* __restrict__ s0_arr, const float* __restrict__ q_arr,
    float2* __restrict__ part) {
  const int t   = blockIdx.x * 256 + threadIdx.x;
  const int idx = t * 4;              // flat (B,S,R)
  const int r   = idx & (Rc - 1);
  const int bs  = idx >> 7;
  const int b   = bs >> 6;

  const float m = mask[bs];
  const float4 al  = *reinterpret_cast<const float4*>(alpha + idx);
  const float4 s0v = *reinterpret_cast<const float4*>(s0_arr + b * Rc + r);
  const float4 qv  = *reinterpret_cast<const float4*>(q_arr + b * Rc + r);

  float sp_sum = 0.f, aq_sum = 0.f;
  const float av[4]  = {al.x, al.y, al.z, al.w};
  const float sv[4]  = {s0v.x, s0v.y, s0v.z, s0v.w};
  const float qvv[4] = {qv.x, qv.y, qv.z, qv.w};
  #pragma unroll
  for (int j = 0; j < 4; ++j) {
    const float a  = (av[j] - 0.1f) * m;
    const float sc = -(a * a * a) * sv[j];
    sp_sum += fmaxf(sc, 0.f) + log1pf(__expf(-fabsf(sc)));
    aq_sum += a * a * qvv[j];
  }

  #pragma unroll
  for (int off = 32; off > 0; off >>= 1) {
    sp_sum += __shfl_down(sp_sum, off, 64);
    aq_sum += __shfl_down(aq_sum, off, 64);
  }
  __shared__ float red[8];
  const int lane = threadIdx.x & 63, wid = threadIdx.x >> 6;
  if (lane == 0) {
    red[wid]     = sp_sum;
    red[wid + 4] = aq_sum;
  }
  __syncthreads();
  if (threadIdx.x == 0) {
    part[blockIdx.x] =
        make_float2(red[0] + red[1] + red[2] + red[3],
                    red[4] + red[5] + red[6] + red[7]);
  }
}

// ---------------------------------------------------------------------------
// Kernel 3: finalize (1 block). Reduce 2048 partials + mask sum, combine.
// ---------------------------------------------------------------------------
__global__ __launch_bounds__(256) void finalize_kernel(
    const float* __restrict__ mask, const float2* __restrict__ part,
    float* __restrict__ out) {
  double sp = 0.0, aq = 0.0;
  float msum = 0.f;
  #pragma unroll
  for (int j = 0; j < 8; ++j) {          // 2048 partials / 256 threads
    const float2 p = part[threadIdx.x + j * 256];
    sp += (double)p.x;
    aq += (double)p.y;
  }
  const float4* m4 = reinterpret_cast<const float4*>(mask);
  #pragma unroll
  for (int j = 0; j < 16; ++j) {         // 4096 float4 / 256 threads
    const float4 v = m4[threadIdx.x + j * 256];
    msum += v.x + v.y + v.z + v.w;
  }

  #pragma unroll
  for (int off = 32; off > 0; off >>= 1) {
    sp   += __shfl_down(sp, off, 64);
    aq   += __shfl_down(aq, off, 64);
    msum += __shfl_down(msum, off, 64);
  }
  __shared__ double dred[8];
  __shared__ float fred[4];
  const int lane = threadIdx.x & 63, wid = threadIdx.x >> 6;
  if (lane == 0) {
    dred[wid]     = sp;
    dred[wid + 4] = aq;
    fred[wid]     = msum;
  }
  __syncthreads();
  if (threadIdx.x == 0) {
    const double spt = dred[0] + dred[1] + dred[2] + dred[3];
    const double aqt = dred[4] + dred[5] + dred[6] + dred[7];
    const double numtrue = (double)(fred[0] + fred[1] + fred[2] + fred[3]);
    const double denom = (double)Bc * Sc * Rc * Dc;
    out[0] = (float)(spt / numtrue + 0.01 * aqt / denom);
  }
}

// ---------------------------------------------------------------------------
extern "C" void kernel_launch(void* const* d_in, const int* in_sizes, int n_in,
                              void* d_out, int out_size, void* d_ws, size_t ws_size,
                              hipStream_t stream) {
  const float* tri   = (const float*)d_in[0];  // (B, R, F)
  const float* alpha = (const float*)d_in[1];  // (B, S, R)
  const float* mask  = (const float*)d_in[2];  // (B, S)
  float* out = (float*)d_out;

  // ws layout (all fully overwritten before read; no zeroing needed):
  //   s0[B*R] floats | q[B*R] floats | part[2048] float2
  float*  s0_arr = (float*)d_ws;
  float*  q_arr  = s0_arr + Bc * Rc;
  float2* part   = (float2*)(q_arr + Bc * Rc);

  rowstats_kernel<<<(Bc * Rc) / (4 * RPW), 256, 0, stream>>>(tri, s0_arr, q_arr);
  score_kernel<<<(Bc * Sc * Rc) / (4 * 256), 256, 0, stream>>>(alpha, mask,
                                                               s0_arr, q_arr, part);
  finalize_kernel<<<1, 256, 0, stream>>>(mask, part, out);
}

// Round 6
// 283.149 us; speedup vs baseline: 1.0091x; 1.0091x over previous
//
#include <hip/hip_runtime.h>

// Problem constants (from reference: B=256, S=64, R=128, F=1536, D=256)
constexpr int Bc = 256;
constexpr int Sc = 64;
constexpr int Rc = 128;
constexpr int Fc = 1536;
constexpr int Dc = 256;  // F/6

// ---------------------------------------------------------------------------
// Kernel 1: per-row (b,r) stats via LDS staging.
// 512-thread block (8 waves) owns 8 consecutive rows = 48 KB.
//  Phase A: stream the block's contiguous 48 KB chunk into LDS, linear
//           layout, 6 coalesced float4 loads per thread (identical global
//           pattern to the 6.9 TB/s fill/copy kernels).
//  Phase B: wave w reduces row w from LDS (6 ds_read_b128 per lane,
//           16 B lane stride -> bank-conflict-free), shuffle-reduce.
// ---------------------------------------------------------------------------
constexpr int RPB = 8;                    // rows per block
constexpr int F4_PER_BLOCK = RPB * (Fc / 4);  // 3072 float4 = 48 KB

__device__ __forceinline__ void accum_term(float h_re, float h_im,
                                           float r_re, float r_im,
                                           float t_re, float t_im,
                                           float& s0, float& q) {
  s0 += r_re * (h_re * t_re + h_im * t_im) + r_im * (h_re * t_im - h_im * t_re);
  q  += h_re * h_re + h_im * h_im + r_re * r_re + r_im * r_im + t_re * t_re + t_im * t_im;
}

__global__ __launch_bounds__(512) void rowstats_kernel(
    const float* __restrict__ tri, float* __restrict__ s0_out,
    float* __restrict__ q_out) {
  __shared__ float4 lds[F4_PER_BLOCK];  // 48 KB

  const int tid = threadIdx.x;
  const size_t base = (size_t)blockIdx.x * F4_PER_BLOCK;
  const float4* __restrict__ g = reinterpret_cast<const float4*>(tri) + base;

  // ---- Phase A: linear stream global -> LDS ----
  #pragma unroll
  for (int k = 0; k < 6; ++k) {
    lds[k * 512 + tid] = g[k * 512 + tid];
  }
  __syncthreads();

  // ---- Phase B: wave w reduces row w from LDS ----
  const int w    = tid >> 6;   // 0..7
  const int lane = tid & 63;
  const int rbase = w * (Fc / 4);  // float4 offset of row w in LDS

  const float4 hre = lds[rbase + 0 * 64 + lane];
  const float4 him = lds[rbase + 1 * 64 + lane];
  const float4 rre = lds[rbase + 2 * 64 + lane];
  const float4 rim = lds[rbase + 3 * 64 + lane];
  const float4 tre = lds[rbase + 4 * 64 + lane];
  const float4 tim = lds[rbase + 5 * 64 + lane];

  float s0 = 0.f, q = 0.f;
  accum_term(hre.x, him.x, rre.x, rim.x, tre.x, tim.x, s0, q);
  accum_term(hre.y, him.y, rre.y, rim.y, tre.y, tim.y, s0, q);
  accum_term(hre.z, him.z, rre.z, rim.z, tre.z, tim.z, s0, q);
  accum_term(hre.w, him.w, rre.w, rim.w, tre.w, tim.w, s0, q);

  #pragma unroll
  for (int off = 32; off > 0; off >>= 1) {
    s0 += __shfl_down(s0, off, 64);
    q  += __shfl_down(q, off, 64);
  }
  if (lane == 0) {
    const int row = blockIdx.x * RPB + w;
    s0_out[row] = s0;
    q_out[row]  = q;
  }
}

// ---------------------------------------------------------------------------
// Kernel 2: score + regul partials over (b,s,r). No atomics: one float2
// partial per block.
// ---------------------------------------------------------------------------
__global__ __launch_bounds__(256) void score_kernel(
    const float* __restrict__ alpha, const float* __restrict__ mask,
    const float* __restrict__ s0_arr, const float* __restrict__ q_arr,
    float2* __restrict__ part) {
  const int t   = blockIdx.x * 256 + threadIdx.x;
  const int idx = t * 4;              // flat (B,S,R)
  const int r   = idx & (Rc - 1);
  const int bs  = idx >> 7;
  const int b   = bs >> 6;

  const float m = mask[bs];
  const float4 al  = *reinterpret_cast<const float4*>(alpha + idx);
  const float4 s0v = *reinterpret_cast<const float4*>(s0_arr + b * Rc + r);
  const float4 qv  = *reinterpret_cast<const float4*>(q_arr + b * Rc + r);

  float sp_sum = 0.f, aq_sum = 0.f;
  const float av[4]  = {al.x, al.y, al.z, al.w};
  const float sv[4]  = {s0v.x, s0v.y, s0v.z, s0v.w};
  const float qvv[4] = {qv.x, qv.y, qv.z, qv.w};
  #pragma unroll
  for (int j = 0; j < 4; ++j) {
    const float a  = (av[j] - 0.1f) * m;
    const float sc = -(a * a * a) * sv[j];
    sp_sum += fmaxf(sc, 0.f) + log1pf(__expf(-fabsf(sc)));
    aq_sum += a * a * qvv[j];
  }

  #pragma unroll
  for (int off = 32; off > 0; off >>= 1) {
    sp_sum += __shfl_down(sp_sum, off, 64);
    aq_sum += __shfl_down(aq_sum, off, 64);
  }
  __shared__ float red[8];
  const int lane = threadIdx.x & 63, wid = threadIdx.x >> 6;
  if (lane == 0) {
    red[wid]     = sp_sum;
    red[wid + 4] = aq_sum;
  }
  __syncthreads();
  if (threadIdx.x == 0) {
    part[blockIdx.x] =
        make_float2(red[0] + red[1] + red[2] + red[3],
                    red[4] + red[5] + red[6] + red[7]);
  }
}

// ---------------------------------------------------------------------------
// Kernel 3: finalize (1 block). Reduce 2048 partials + mask sum, combine.
// ---------------------------------------------------------------------------
__global__ __launch_bounds__(256) void finalize_kernel(
    const float* __restrict__ mask, const float2* __restrict__ part,
    float* __restrict__ out) {
  double sp = 0.0, aq = 0.0;
  float msum = 0.f;
  #pragma unroll
  for (int j = 0; j < 8; ++j) {          // 2048 partials / 256 threads
    const float2 p = part[threadIdx.x + j * 256];
    sp += (double)p.x;
    aq += (double)p.y;
  }
  const float4* m4 = reinterpret_cast<const float4*>(mask);
  #pragma unroll
  for (int j = 0; j < 16; ++j) {         // 4096 float4 / 256 threads
    const float4 v = m4[threadIdx.x + j * 256];
    msum += v.x + v.y + v.z + v.w;
  }

  #pragma unroll
  for (int off = 32; off > 0; off >>= 1) {
    sp   += __shfl_down(sp, off, 64);
    aq   += __shfl_down(aq, off, 64);
    msum += __shfl_down(msum, off, 64);
  }
  __shared__ double dred[8];
  __shared__ float fred[4];
  const int lane = threadIdx.x & 63, wid = threadIdx.x >> 6;
  if (lane == 0) {
    dred[wid]     = sp;
    dred[wid + 4] = aq;
    fred[wid]     = msum;
  }
  __syncthreads();
  if (threadIdx.x == 0) {
    const double spt = dred[0] + dred[1] + dred[2] + dred[3];
    const double aqt = dred[4] + dred[5] + dred[6] + dred[7];
    const double numtrue = (double)(fred[0] + fred[1] + fred[2] + fred[3]);
    const double denom = (double)Bc * Sc * Rc * Dc;
    out[0] = (float)(spt / numtrue + 0.01 * aqt / denom);
  }
}

// ---------------------------------------------------------------------------
extern "C" void kernel_launch(void* const* d_in, const int* in_sizes, int n_in,
                              void* d_out, int out_size, void* d_ws, size_t ws_size,
                              hipStream_t stream) {
  const float* tri   = (const float*)d_in[0];  // (B, R, F)
  const float* alpha = (const float*)d_in[1];  // (B, S, R)
  const float* mask  = (const float*)d_in[2];  // (B, S)
  float* out = (float*)d_out;

  // ws layout (all fully overwritten before read; no zeroing needed):
  //   s0[B*R] floats | q[B*R] floats | part[2048] float2
  float*  s0_arr = (float*)d_ws;
  float*  q_arr  = s0_arr + Bc * Rc;
  float2* part   = (float2*)(q_arr + Bc * Rc);

  rowstats_kernel<<<(Bc * Rc) / RPB, 512, 0, stream>>>(tri, s0_arr, q_arr);
  score_kernel<<<(Bc * Sc * Rc) / (4 * 256), 256, 0, stream>>>(alpha, mask,
                                                               s0_arr, q_arr, part);
  finalize_kernel<<<1, 256, 0, stream>>>(mask, part, out);
}